// Round 3
// baseline (1672.303 us; speedup 1.0000x reference)
//
#include <hip/hip_runtime.h>
#include <math.h>

#define F_IN 256
#define HID  64
#define SPAN 64            // nodes per bucket (dst >> 6)
#define CAP  2048          // max edges per bucket (mean 1024, sigma 32 for uniform random)

// ---------------------------------------------------------------------------
// Zero bucket counters
// ---------------------------------------------------------------------------
__global__ void k_zero(int* __restrict__ b, int n) {
    int i = blockIdx.x * blockDim.x + threadIdx.x;
    if (i < n) b[i] = 0;
}

// ---------------------------------------------------------------------------
// Bin edges by coarse dst bucket. Entry = (src<<6) | (dst&63).
// Writes cluster at bucket frontiers -> mostly-filled cache lines.
// ---------------------------------------------------------------------------
__global__ void k_bin(const int* __restrict__ src, const int* __restrict__ dst,
                      int* __restrict__ bcnt, int* __restrict__ bbuf, int E) {
    int e = blockIdx.x * blockDim.x + threadIdx.x;
    if (e >= E) return;
    int s = src[e];
    int d = dst[e];
    int b = d >> 6;
    int pos = atomicAdd(&bcnt[b], 1);
    if (pos < CAP)   // statistically never exceeded; guard avoids corruption
        bbuf[(size_t)b * CAP + pos] = (s << 6) | (d & 63);
}

// ---------------------------------------------------------------------------
// Per-bucket degree count -> dinv (deg includes +1 self loop)
// ---------------------------------------------------------------------------
__global__ __launch_bounds__(256) void k_deg(const int* __restrict__ bcnt,
                                             const int* __restrict__ bbuf,
                                             float* __restrict__ dinv, int n) {
    __shared__ int c[SPAN];
    int b = blockIdx.x, t = threadIdx.x;
    if (t < SPAN) c[t] = 1;   // self loop
    __syncthreads();
    int cnt = min(bcnt[b], CAP);
    const int* ebase = bbuf + (size_t)b * CAP;
    for (int i = t; i < cnt; i += 256) atomicAdd(&c[ebase[i] & 63], 1);
    __syncthreads();
    int node = b * SPAN + t;
    if (t < SPAN && node < n) dinv[node] = rsqrtf((float)c[t]);
}

// ---------------------------------------------------------------------------
// fp32 GEMM: C[nrows x 64] = (A[nrows x K] @ B[K x 64]) * dinv[row]
// ---------------------------------------------------------------------------
template <int K>
__global__ __launch_bounds__(256) void k_gemm64(const float* __restrict__ A,
                                                const float* __restrict__ B,
                                                const float* __restrict__ dinv,
                                                float* __restrict__ C, int nrows) {
    __shared__ float As[16][68];
    __shared__ float Bs[16][64];

    int tid = threadIdx.x;
    int tx = tid & 15;
    int ty = tid >> 4;
    int row0 = blockIdx.x * 64;

    int arow = tid >> 2;
    int ak   = (tid & 3) * 4;
    int brow = tid >> 4;
    int bcol = (tid & 15) * 4;

    float acc[4][4] = {};

    for (int k0 = 0; k0 < K; k0 += 16) {
        int gr = row0 + arow;
        float4 av = make_float4(0.f, 0.f, 0.f, 0.f);
        if (gr < nrows) av = *(const float4*)(A + (size_t)gr * K + k0 + ak);
        float4 bv = *(const float4*)(B + (size_t)(k0 + brow) * 64 + bcol);
        __syncthreads();
        As[ak + 0][arow] = av.x;
        As[ak + 1][arow] = av.y;
        As[ak + 2][arow] = av.z;
        As[ak + 3][arow] = av.w;
        *(float4*)&Bs[brow][bcol] = bv;
        __syncthreads();
#pragma unroll
        for (int kk = 0; kk < 16; kk++) {
            float4 a = *(const float4*)&As[kk][4 * ty];
            float4 b = *(const float4*)&Bs[kk][4 * tx];
            acc[0][0] += a.x * b.x; acc[0][1] += a.x * b.y; acc[0][2] += a.x * b.z; acc[0][3] += a.x * b.w;
            acc[1][0] += a.y * b.x; acc[1][1] += a.y * b.y; acc[1][2] += a.y * b.z; acc[1][3] += a.y * b.w;
            acc[2][0] += a.z * b.x; acc[2][1] += a.z * b.y; acc[2][2] += a.z * b.z; acc[2][3] += a.z * b.w;
            acc[3][0] += a.w * b.x; acc[3][1] += a.w * b.y; acc[3][2] += a.w * b.z; acc[3][3] += a.w * b.w;
        }
    }
#pragma unroll
    for (int i = 0; i < 4; i++) {
        int row = row0 + 4 * ty + i;
        if (row < nrows) {
            float di = dinv[row];
            float4 o = make_float4(acc[i][0] * di, acc[i][1] * di, acc[i][2] * di, acc[i][3] * di);
            *(float4*)(C + (size_t)row * 64 + 4 * tx) = o;
        }
    }
}

// ---------------------------------------------------------------------------
// Bucket aggregation, 64 features. One block (4 waves) per bucket of 64 nodes.
// hs rows are pre-scaled by dinv[src].  acc[node][feat] in LDS via ds_add_f32.
//   v = relu(dinv[d] * (hs[d] + sum_{e->d} hs[src]) + bias)
// MODE 0: out[d] = v (64-wide)     MODE 1: h3[d] = (v @ W3) * dinv[d]
// ---------------------------------------------------------------------------
template <int MODE>
__global__ __launch_bounds__(256) void k_agg(const float* __restrict__ hs,
                                             const float* __restrict__ dinv,
                                             const int* __restrict__ bcnt,
                                             const int* __restrict__ bbuf,
                                             const float* __restrict__ bias,
                                             const float* __restrict__ W3,
                                             float* __restrict__ out, int n) {
    __shared__ float acc[SPAN * 64];   // 16 KB
    int b = blockIdx.x, t = threadIdx.x;
    int n0 = b * SPAN;

    // init with self-loop term
    for (int idx = t; idx < SPAN * 64; idx += 256) {
        int ld = idx >> 6, lane2 = idx & 63;
        int node = n0 + ld;
        acc[idx] = (node < n) ? hs[(size_t)node * 64 + lane2] : 0.f;
    }
    __syncthreads();

    int cnt = min(bcnt[b], CAP);
    const int* ebase = bbuf + (size_t)b * CAP;
    int w = t >> 6, lane = t & 63;

    for (int i = w * 4; i < cnt; i += 16) {
        int m = cnt - i;
        int4 p = *(const int4*)(ebase + i);   // i%4==0, within CAP
        // branchless: clamp tail entries to entry 0, zero their contribution
        int px = p.x;
        int py = (m > 1) ? p.y : px;
        int pz = (m > 2) ? p.z : px;
        int pw = (m > 3) ? p.w : px;
        float f1 = (m > 1) ? 1.f : 0.f;
        float f2 = (m > 2) ? 1.f : 0.f;
        float f3 = (m > 3) ? 1.f : 0.f;
        float v0 = hs[(size_t)(px >> 6) * 64 + lane];
        float v1 = hs[(size_t)(py >> 6) * 64 + lane] * f1;
        float v2 = hs[(size_t)(pz >> 6) * 64 + lane] * f2;
        float v3 = hs[(size_t)(pw >> 6) * 64 + lane] * f3;
        atomicAdd(&acc[(px & 63) * 64 + lane], v0);
        atomicAdd(&acc[(py & 63) * 64 + lane], v1);
        atomicAdd(&acc[(pz & 63) * 64 + lane], v2);
        atomicAdd(&acc[(pw & 63) * 64 + lane], v3);
    }
    __syncthreads();

    if (MODE == 0) {
        for (int idx = t; idx < SPAN * 64; idx += 256) {
            int ld = idx >> 6, lane2 = idx & 63;
            int node = n0 + ld;
            if (node < n)
                out[(size_t)node * 64 + lane2] =
                    fmaxf(acc[idx] * dinv[node] + bias[lane2], 0.f);
        }
    } else {
        float2 w3 = ((const float2*)W3)[lane];
        float bl = bias[lane];
#pragma unroll 4
        for (int j = 0; j < 16; j++) {
            int ld = w * 16 + j;
            int node = n0 + ld;
            if (node >= n) break;
            float dii = dinv[node];
            float v = fmaxf(acc[ld * 64 + lane] * dii + bl, 0.f);
            float p0 = v * w3.x;
            float p1 = v * w3.y;
#pragma unroll
            for (int off = 32; off > 0; off >>= 1) {
                p0 += __shfl_xor(p0, off, 64);
                p1 += __shfl_xor(p1, off, 64);
            }
            if (lane == 0) ((float2*)out)[node] = make_float2(p0 * dii, p1 * dii);
        }
    }
}

// ---------------------------------------------------------------------------
// Final layer: 2-wide bucket aggregation + bias + log_softmax
// ---------------------------------------------------------------------------
__global__ __launch_bounds__(256) void k_last(const float2* __restrict__ h3s,
                                              const float* __restrict__ dinv,
                                              const int* __restrict__ bcnt,
                                              const int* __restrict__ bbuf,
                                              const float* __restrict__ b3,
                                              float* __restrict__ out, int n) {
    __shared__ float ax[SPAN], ay[SPAN];
    int b = blockIdx.x, t = threadIdx.x;
    int n0 = b * SPAN;
    if (t < SPAN) {
        int node = n0 + t;
        float2 h = (node < n) ? h3s[node] : make_float2(0.f, 0.f);
        ax[t] = h.x;
        ay[t] = h.y;
    }
    __syncthreads();
    int cnt = min(bcnt[b], CAP);
    const int* ebase = bbuf + (size_t)b * CAP;
    for (int i = t; i < cnt; i += 256) {
        int p = ebase[i];
        float2 hv = h3s[p >> 6];
        int ld = p & 63;
        atomicAdd(&ax[ld], hv.x);
        atomicAdd(&ay[ld], hv.y);
    }
    __syncthreads();
    int node = n0 + t;
    if (t < SPAN && node < n) {
        float dii = dinv[node];
        float l0 = ax[t] * dii + b3[0];
        float l1 = ay[t] * dii + b3[1];
        float m = fmaxf(l0, l1);
        float lse = m + logf(expf(l0 - m) + expf(l1 - m));
        ((float2*)out)[node] = make_float2(l0 - lse, l1 - lse);
    }
}

// ---------------------------------------------------------------------------
// Launch
// ---------------------------------------------------------------------------
extern "C" void kernel_launch(void* const* d_in, const int* in_sizes, int n_in,
                              void* d_out, int out_size, void* d_ws, size_t ws_size,
                              hipStream_t stream) {
    const float* x   = (const float*)d_in[0];
    const int*   ei  = (const int*)d_in[1];
    const float* W1  = (const float*)d_in[2];
    const float* b1  = (const float*)d_in[3];
    const float* W2  = (const float*)d_in[4];
    const float* b2  = (const float*)d_in[5];
    const float* W3  = (const float*)d_in[6];
    const float* b3  = (const float*)d_in[7];
    float* out = (float*)d_out;

    const int N = in_sizes[0] / F_IN;   // 100000
    const int E = in_sizes[1] / 2;      // 1600000
    const int* src = ei;
    const int* dst = ei + E;
    const int NB = (N + SPAN - 1) / SPAN;   // 1563 buckets

    // workspace bump allocator (256B aligned)
    char* p = (char*)d_ws;
    auto alloc = [&](size_t bytes) -> void* {
        void* r = (void*)p;
        p += (bytes + 255) & ~(size_t)255;
        return r;
    };
    int*   bcnt = (int*)alloc((size_t)NB * 4);
    int*   bbuf = (int*)alloc((size_t)NB * CAP * 4);   // 12.8 MB
    float* dinv = (float*)alloc((size_t)N * 4);
    float* bufA = (float*)alloc((size_t)N * HID * 4);
    float* bufB = (float*)alloc((size_t)N * HID * 4);
    float* h3   = (float*)alloc((size_t)N * 2 * 4);

    const int T = 256;

    k_zero<<<(NB + T - 1) / T, T, 0, stream>>>(bcnt, NB);
    k_bin<<<(E + T - 1) / T, T, 0, stream>>>(src, dst, bcnt, bbuf, E);
    k_deg<<<NB, T, 0, stream>>>(bcnt, bbuf, dinv, N);

    int gemmBlocks = (N + 63) / 64;
    k_gemm64<F_IN><<<gemmBlocks, T, 0, stream>>>(x, W1, dinv, bufA, N);
    k_agg<0><<<NB, T, 0, stream>>>(bufA, dinv, bcnt, bbuf, b1, nullptr, bufB, N);

    k_gemm64<HID><<<gemmBlocks, T, 0, stream>>>(bufB, W2, dinv, bufA, N);
    k_agg<1><<<NB, T, 0, stream>>>(bufA, dinv, bcnt, bbuf, b2, W3, h3, N);

    k_last<<<NB, T, 0, stream>>>((const float2*)h3, dinv, bcnt, bbuf, b3, out, N);
}

// Round 4
// 419.301 us; speedup vs baseline: 3.9883x; 3.9883x over previous
//
#include <hip/hip_runtime.h>
#include <math.h>

#define F_IN 256
#define HID  64
#define BSH  8              // bucket = dst >> 8 (256 nodes per bucket)
#define BSPAN 256
#define CHUNK 16384         // edges per sort block (64 per thread)
#define NBK_MAX 512

// ---------------------------------------------------------------------------
// Pass 1: per-chunk histogram over coarse dst buckets
// cntT layout: [bucket][chunk]  (bucket-major so its scan gives write offsets)
// ---------------------------------------------------------------------------
__global__ __launch_bounds__(256) void k_hist(const int* __restrict__ dst,
                                              int* __restrict__ cntT,
                                              int E, int NCH, int NBK) {
    __shared__ int hist[NBK_MAX];
    int t = threadIdx.x, c = blockIdx.x;
    hist[t] = 0; hist[t + 256] = 0;
    __syncthreads();
    int base = c * CHUNK;
#pragma unroll 4
    for (int j = 0; j < CHUNK / 256; j++) {
        int e = base + j * 256 + t;
        if (e < E) atomicAdd(&hist[dst[e] >> BSH], 1);
    }
    __syncthreads();
    for (int b = t; b < NBK; b += 256) cntT[b * NCH + c] = hist[b];
}

// ---------------------------------------------------------------------------
// Exclusive scan of cntT (S elements) -> off, plus sentinel off[S] = total
// ---------------------------------------------------------------------------
__global__ __launch_bounds__(256) void k_scanA(const int* __restrict__ cntT,
                                               int* __restrict__ off,
                                               int* __restrict__ partials, int S) {
    __shared__ int sh[256];
    int tid = threadIdx.x;
    int base = blockIdx.x * 1024 + tid * 4;
    int v[4];
    int s = 0;
#pragma unroll
    for (int j = 0; j < 4; j++) {
        int idx = base + j;
        v[j] = (idx < S) ? cntT[idx] : 0;
        s += v[j];
    }
    sh[tid] = s;
    __syncthreads();
    int mysum = s;
    for (int o = 1; o < 256; o <<= 1) {
        int tv = (tid >= o) ? sh[tid - o] : 0;
        __syncthreads();
        sh[tid] += tv;
        __syncthreads();
    }
    int pref = sh[tid] - mysum;
#pragma unroll
    for (int j = 0; j < 4; j++) {
        int idx = base + j;
        if (idx < S) off[idx] = pref;
        pref += v[j];
    }
    if (tid == 255) partials[blockIdx.x] = sh[255];
}

__global__ void k_scanB(int* __restrict__ partials, int* __restrict__ off,
                        int nblk, int S) {
    if (blockIdx.x == 0 && threadIdx.x == 0) {
        int run = 0;
        for (int b = 0; b < nblk; b++) { int t = partials[b]; partials[b] = run; run += t; }
        off[S] = run;   // == E
    }
}

__global__ void k_scanC(int* __restrict__ off, const int* __restrict__ partials, int S) {
    int i = blockIdx.x * blockDim.x + threadIdx.x;
    if (i < S) off[i] += partials[i >> 10];
}

// ---------------------------------------------------------------------------
// Pass 2: scatter edges into bucket-grouped ebuf using exact per-(bucket,chunk)
// offsets. Each block's writes per bucket are contiguous -> near-full lines.
// Entry = (src<<8) | (dst & 255)
// ---------------------------------------------------------------------------
__global__ __launch_bounds__(256) void k_sortwrite(const int* __restrict__ src,
                                                   const int* __restrict__ dst,
                                                   const int* __restrict__ off,
                                                   int* __restrict__ ebuf,
                                                   int E, int NCH, int NBK) {
    __shared__ int cur[NBK_MAX];
    int t = threadIdx.x, c = blockIdx.x;
    for (int b = t; b < NBK; b += 256) cur[b] = off[b * NCH + c];
    __syncthreads();
    int base = c * CHUNK;
#pragma unroll 4
    for (int j = 0; j < CHUNK / 256; j++) {
        int e = base + j * 256 + t;
        if (e < E) {
            int s = src[e];
            int d = dst[e];
            int pos = atomicAdd(&cur[d >> BSH], 1);
            ebuf[pos] = (s << BSH) | (d & (BSPAN - 1));
        }
    }
}

// ---------------------------------------------------------------------------
// Pass 3: per-bucket node-level CSR: rp, dinv, node-sorted esrc
// ---------------------------------------------------------------------------
__global__ __launch_bounds__(256) void k_bucket_csr(const int* __restrict__ off,
                                                    const int* __restrict__ ebuf,
                                                    int* __restrict__ rp,
                                                    float* __restrict__ dinv,
                                                    int* __restrict__ esrc,
                                                    int N, int NCH, int NBK) {
    __shared__ int cnt[BSPAN];
    __shared__ int sh[BSPAN];
    int b = blockIdx.x, t = threadIdx.x;
    int base = off[b * NCH];
    int end  = off[(b + 1) * NCH];   // sentinel covers b == NBK-1

    cnt[t] = 0;
    __syncthreads();
    for (int i = base + t; i < end; i += 256) atomicAdd(&cnt[ebuf[i] & (BSPAN - 1)], 1);
    __syncthreads();

    int c = cnt[t];
    sh[t] = c;
    __syncthreads();
    for (int o = 1; o < 256; o <<= 1) {
        int tv = (t >= o) ? sh[t - o] : 0;
        __syncthreads();
        sh[t] += tv;
        __syncthreads();
    }
    int excl = sh[t] - c;

    int node = (b << BSH) + t;
    if (node < N) {
        rp[node] = base + excl;
        dinv[node] = rsqrtf((float)(1 + c));   // +1 self loop
    }
    if (b == NBK - 1 && t == 0) rp[N] = end;
    __syncthreads();

    cnt[t] = base + excl;   // running cursor (global position)
    __syncthreads();
    for (int i = base + t; i < end; i += 256) {
        int v = ebuf[i];
        int p = atomicAdd(&cnt[v & (BSPAN - 1)], 1);
        esrc[p] = v >> BSH;
    }
}

// ---------------------------------------------------------------------------
// fp32 GEMM: C[nrows x 64] = (A[nrows x K] @ B[K x 64]) * dinv[row]
// ---------------------------------------------------------------------------
template <int K>
__global__ __launch_bounds__(256) void k_gemm64(const float* __restrict__ A,
                                                const float* __restrict__ B,
                                                const float* __restrict__ dinv,
                                                float* __restrict__ C, int nrows) {
    __shared__ float As[16][68];
    __shared__ float Bs[16][64];

    int tid = threadIdx.x;
    int tx = tid & 15;
    int ty = tid >> 4;
    int row0 = blockIdx.x * 64;

    int arow = tid >> 2;
    int ak   = (tid & 3) * 4;
    int brow = tid >> 4;
    int bcol = (tid & 15) * 4;

    float acc[4][4] = {};

    for (int k0 = 0; k0 < K; k0 += 16) {
        int gr = row0 + arow;
        float4 av = make_float4(0.f, 0.f, 0.f, 0.f);
        if (gr < nrows) av = *(const float4*)(A + (size_t)gr * K + k0 + ak);
        float4 bv = *(const float4*)(B + (size_t)(k0 + brow) * 64 + bcol);
        __syncthreads();
        As[ak + 0][arow] = av.x;
        As[ak + 1][arow] = av.y;
        As[ak + 2][arow] = av.z;
        As[ak + 3][arow] = av.w;
        *(float4*)&Bs[brow][bcol] = bv;
        __syncthreads();
#pragma unroll
        for (int kk = 0; kk < 16; kk++) {
            float4 a = *(const float4*)&As[kk][4 * ty];
            float4 bq = *(const float4*)&Bs[kk][4 * tx];
            acc[0][0] += a.x * bq.x; acc[0][1] += a.x * bq.y; acc[0][2] += a.x * bq.z; acc[0][3] += a.x * bq.w;
            acc[1][0] += a.y * bq.x; acc[1][1] += a.y * bq.y; acc[1][2] += a.y * bq.z; acc[1][3] += a.y * bq.w;
            acc[2][0] += a.z * bq.x; acc[2][1] += a.z * bq.y; acc[2][2] += a.z * bq.z; acc[2][3] += a.z * bq.w;
            acc[3][0] += a.w * bq.x; acc[3][1] += a.w * bq.y; acc[3][2] += a.w * bq.z; acc[3][3] += a.w * bq.w;
        }
    }
#pragma unroll
    for (int i = 0; i < 4; i++) {
        int row = row0 + 4 * ty + i;
        if (row < nrows) {
            float di = dinv[row];
            float4 o = make_float4(acc[i][0] * di, acc[i][1] * di, acc[i][2] * di, acc[i][3] * di);
            *(float4*)(C + (size_t)row * 64 + 4 * tx) = o;
        }
    }
}

// ---------------------------------------------------------------------------
// Aggregation over CSR, 64 features, one wave per node, 8-deep MLP.
// hs rows pre-scaled by dinv[src]; v = relu(dinv[d]*(hs[d]+sum hs[src])+bias)
// MODE 0: out[d] = v (64-wide)   MODE 1: h3[d] = (v @ W3) * dinv[d]
// ---------------------------------------------------------------------------
template <int MODE>
__global__ __launch_bounds__(256) void k_agg64(const float* __restrict__ hs,
                                               const float* __restrict__ dinv,
                                               const int* __restrict__ rp,
                                               const int* __restrict__ esrc,
                                               const float* __restrict__ bias,
                                               const float* __restrict__ W3,
                                               float* __restrict__ out, int n) {
    int lane = threadIdx.x & 63;
    int nid = blockIdx.x * 4 + (threadIdx.x >> 6);
    if (nid >= n) return;
    nid = __builtin_amdgcn_readfirstlane(nid);   // wave-uniform -> scalar loads

    float dii = dinv[nid];
    int e0 = rp[nid];
    int e1 = rp[nid + 1];

    float a0 = hs[(size_t)nid * 64 + lane];   // self-loop (already *dinv)
    float a1 = 0.f, a2 = 0.f, a3 = 0.f, a4 = 0.f, a5 = 0.f, a6 = 0.f, a7 = 0.f;

    for (int e = e0; e < e1; e += 8) {
        int last = e1 - 1;
        int i0 = esrc[e];
        int i1 = esrc[min(e + 1, last)];
        int i2 = esrc[min(e + 2, last)];
        int i3 = esrc[min(e + 3, last)];
        int i4 = esrc[min(e + 4, last)];
        int i5 = esrc[min(e + 5, last)];
        int i6 = esrc[min(e + 6, last)];
        int i7 = esrc[min(e + 7, last)];
        float v0 = hs[(size_t)i0 * 64 + lane];
        float v1 = hs[(size_t)i1 * 64 + lane];
        float v2 = hs[(size_t)i2 * 64 + lane];
        float v3 = hs[(size_t)i3 * 64 + lane];
        float v4 = hs[(size_t)i4 * 64 + lane];
        float v5 = hs[(size_t)i5 * 64 + lane];
        float v6 = hs[(size_t)i6 * 64 + lane];
        float v7 = hs[(size_t)i7 * 64 + lane];
        a0 += v0;
        a1 += (e + 1 <= last) ? v1 : 0.f;
        a2 += (e + 2 <= last) ? v2 : 0.f;
        a3 += (e + 3 <= last) ? v3 : 0.f;
        a4 += (e + 4 <= last) ? v4 : 0.f;
        a5 += (e + 5 <= last) ? v5 : 0.f;
        a6 += (e + 6 <= last) ? v6 : 0.f;
        a7 += (e + 7 <= last) ? v7 : 0.f;
    }

    float acc = ((a0 + a1) + (a2 + a3)) + ((a4 + a5) + (a6 + a7));
    acc = acc * dii + bias[lane];
    acc = fmaxf(acc, 0.f);

    if (MODE == 0) {
        out[(size_t)nid * 64 + lane] = acc;
    } else {
        float2 w3 = ((const float2*)W3)[lane];
        float p0 = acc * w3.x;
        float p1 = acc * w3.y;
#pragma unroll
        for (int o = 32; o > 0; o >>= 1) {
            p0 += __shfl_xor(p0, o, 64);
            p1 += __shfl_xor(p1, o, 64);
        }
        if (lane == 0) ((float2*)out)[nid] = make_float2(p0 * dii, p1 * dii);
    }
}

// ---------------------------------------------------------------------------
// Final layer: 2-wide aggregation + bias + log_softmax (thread per node)
// ---------------------------------------------------------------------------
__global__ __launch_bounds__(256) void k_final(const float2* __restrict__ h3s,
                                               const float* __restrict__ dinv,
                                               const int* __restrict__ rp,
                                               const int* __restrict__ esrc,
                                               const float* __restrict__ b3,
                                               float* __restrict__ out, int n) {
    int i = blockIdx.x * blockDim.x + threadIdx.x;
    if (i >= n) return;
    float dii = dinv[i];
    float2 h = h3s[i];
    float ax = h.x, ay = h.y;
    float bx = 0.f, by = 0.f, cx = 0.f, cy = 0.f, dx = 0.f, dy = 0.f;
    int e0 = rp[i], e1 = rp[i + 1];
    for (int e = e0; e < e1; e += 4) {
        int last = e1 - 1;
        int s0 = esrc[e];
        int s1 = esrc[min(e + 1, last)];
        int s2 = esrc[min(e + 2, last)];
        int s3 = esrc[min(e + 3, last)];
        float2 v0 = h3s[s0];
        float2 v1 = h3s[s1];
        float2 v2 = h3s[s2];
        float2 v3 = h3s[s3];
        ax += v0.x; ay += v0.y;
        bx += (e + 1 <= last) ? v1.x : 0.f; by += (e + 1 <= last) ? v1.y : 0.f;
        cx += (e + 2 <= last) ? v2.x : 0.f; cy += (e + 2 <= last) ? v2.y : 0.f;
        dx += (e + 3 <= last) ? v3.x : 0.f; dy += (e + 3 <= last) ? v3.y : 0.f;
    }
    float l0 = ((ax + bx) + (cx + dx)) * dii + b3[0];
    float l1 = ((ay + by) + (cy + dy)) * dii + b3[1];
    float m = fmaxf(l0, l1);
    float lse = m + logf(expf(l0 - m) + expf(l1 - m));
    ((float2*)out)[i] = make_float2(l0 - lse, l1 - lse);
}

// ---------------------------------------------------------------------------
// Launch
// ---------------------------------------------------------------------------
extern "C" void kernel_launch(void* const* d_in, const int* in_sizes, int n_in,
                              void* d_out, int out_size, void* d_ws, size_t ws_size,
                              hipStream_t stream) {
    const float* x   = (const float*)d_in[0];
    const int*   ei  = (const int*)d_in[1];
    const float* W1  = (const float*)d_in[2];
    const float* b1  = (const float*)d_in[3];
    const float* W2  = (const float*)d_in[4];
    const float* b2  = (const float*)d_in[5];
    const float* W3  = (const float*)d_in[6];
    const float* b3  = (const float*)d_in[7];
    float* out = (float*)d_out;

    const int N = in_sizes[0] / F_IN;   // 100000
    const int E = in_sizes[1] / 2;      // 1600000
    const int* src = ei;
    const int* dst = ei + E;

    const int NBK = (N + BSPAN - 1) / BSPAN;      // 391
    const int NCH = (E + CHUNK - 1) / CHUNK;      // 98
    const int S   = NBK * NCH;                    // 38318

    // workspace bump allocator (256B aligned)
    char* p = (char*)d_ws;
    auto alloc = [&](size_t bytes) -> void* {
        void* r = (void*)p;
        p += (bytes + 255) & ~(size_t)255;
        return r;
    };
    int*   cntT     = (int*)alloc((size_t)S * 4);
    int*   off      = (int*)alloc((size_t)(S + 1) * 4);
    int*   partials = (int*)alloc(4096);
    int*   ebuf     = (int*)alloc((size_t)E * 4);
    int*   esrc     = (int*)alloc((size_t)E * 4);
    int*   rp       = (int*)alloc((size_t)(N + 1) * 4);
    float* dinv     = (float*)alloc((size_t)N * 4);
    float* bufA     = (float*)alloc((size_t)N * HID * 4);
    float* bufB     = (float*)alloc((size_t)N * HID * 4);
    float* h3       = (float*)alloc((size_t)N * 2 * 4);

    const int T = 256;
    int scanBlocks = (S + 1023) / 1024;

    // CSR build via locality-aware counting sort
    k_hist<<<NCH, T, 0, stream>>>(dst, cntT, E, NCH, NBK);
    k_scanA<<<scanBlocks, T, 0, stream>>>(cntT, off, partials, S);
    k_scanB<<<1, 64, 0, stream>>>(partials, off, scanBlocks, S);
    k_scanC<<<(S + T - 1) / T, T, 0, stream>>>(off, partials, S);
    k_sortwrite<<<NCH, T, 0, stream>>>(src, dst, off, ebuf, E, NCH, NBK);
    k_bucket_csr<<<NBK, T, 0, stream>>>(off, ebuf, rp, dinv, esrc, N, NCH, NBK);

    // layer 1
    int gemmBlocks = (N + 63) / 64;
    k_gemm64<F_IN><<<gemmBlocks, T, 0, stream>>>(x, W1, dinv, bufA, N);
    k_agg64<0><<<(N + 3) / 4, T, 0, stream>>>(bufA, dinv, rp, esrc, b1, nullptr, bufB, N);

    // layer 2 (+ fused GEMM3)
    k_gemm64<HID><<<gemmBlocks, T, 0, stream>>>(bufB, W2, dinv, bufA, N);
    k_agg64<1><<<(N + 3) / 4, T, 0, stream>>>(bufA, dinv, rp, esrc, b2, W3, h3, N);

    // layer 3 + log_softmax
    k_final<<<(N + T - 1) / T, T, 0, stream>>>((const float2*)h3, dinv, rp, esrc, b3, out, N);
}